// Round 7
// baseline (449.830 us; speedup 1.0000x reference)
//
#include <hip/hip_runtime.h>

#define DIM 1024
#define BATCH 4096

typedef __attribute__((ext_vector_type(8))) short short8v;
typedef __attribute__((ext_vector_type(4))) short short4v;
typedef __attribute__((ext_vector_type(4))) float f32x4;

// ---------------------------------------------------------------------------
// DPP wave-wide reductions (VALU pipe; result wave-uniform via readlane 63).
__device__ __forceinline__ float dpp_reduce_bcast(float x) {
  int v = __builtin_bit_cast(int, x);
#define DPP_STEP(ctrl)                                                        \
  {                                                                           \
    int s = __builtin_amdgcn_update_dpp(0, v, ctrl, 0xf, 0xf, true);          \
    v = __builtin_bit_cast(                                                   \
        int, __builtin_bit_cast(float, v) + __builtin_bit_cast(float, s));    \
  }
  DPP_STEP(0x111) DPP_STEP(0x112) DPP_STEP(0x114) DPP_STEP(0x118)
  DPP_STEP(0x142) DPP_STEP(0x143)
#undef DPP_STEP
  return __builtin_bit_cast(float, __builtin_amdgcn_readlane(v, 63));
}

__device__ __forceinline__ void dpp_reduce4_bcast(float* d) {
  int v0 = __builtin_bit_cast(int, d[0]);
  int v1 = __builtin_bit_cast(int, d[1]);
  int v2 = __builtin_bit_cast(int, d[2]);
  int v3 = __builtin_bit_cast(int, d[3]);
#define STEP4(ctrl)                                                           \
  {                                                                           \
    int s0 = __builtin_amdgcn_update_dpp(0, v0, ctrl, 0xf, 0xf, true);        \
    int s1 = __builtin_amdgcn_update_dpp(0, v1, ctrl, 0xf, 0xf, true);        \
    int s2 = __builtin_amdgcn_update_dpp(0, v2, ctrl, 0xf, 0xf, true);        \
    int s3 = __builtin_amdgcn_update_dpp(0, v3, ctrl, 0xf, 0xf, true);        \
    v0 = __builtin_bit_cast(int, __builtin_bit_cast(float, v0) +              \
                                     __builtin_bit_cast(float, s0));          \
    v1 = __builtin_bit_cast(int, __builtin_bit_cast(float, v1) +              \
                                     __builtin_bit_cast(float, s1));          \
    v2 = __builtin_bit_cast(int, __builtin_bit_cast(float, v2) +              \
                                     __builtin_bit_cast(float, s2));          \
    v3 = __builtin_bit_cast(int, __builtin_bit_cast(float, v3) +              \
                                     __builtin_bit_cast(float, s3));          \
  }
  STEP4(0x111) STEP4(0x112) STEP4(0x114) STEP4(0x118) STEP4(0x142) STEP4(0x143)
#undef STEP4
  d[0] = __builtin_bit_cast(float, __builtin_amdgcn_readlane(v0, 63));
  d[1] = __builtin_bit_cast(float, __builtin_amdgcn_readlane(v1, 63));
  d[2] = __builtin_bit_cast(float, __builtin_amdgcn_readlane(v2, 63));
  d[3] = __builtin_bit_cast(float, __builtin_amdgcn_readlane(v3, 63));
}

// bf16 split helpers (RNE).
__device__ __forceinline__ short f2bf(float f) {
  unsigned u = __builtin_bit_cast(unsigned, f);
  u += 0x7FFFu + ((u >> 16) & 1u);
  return (short)(u >> 16);
}
__device__ __forceinline__ float bf2f(short h) {
  unsigned u = ((unsigned)(unsigned short)h) << 16;
  return __builtin_bit_cast(float, u);
}

// ---------------------------------------------------------------------------
// 2/||row||^2 for all rows of U and V. One wave per row.
__global__ __launch_bounds__(256) void prep_k(const float* __restrict__ U,
                                              const float* __restrict__ V,
                                              float* __restrict__ tinu,
                                              float* __restrict__ tinv) {
  int gw = (blockIdx.x * 256 + threadIdx.x) >> 6;
  int lane = threadIdx.x & 63;
  if (gw >= 2048) return;
  const float* src = (gw < 1024) ? (U + (size_t)gw * DIM) : (V + (size_t)(gw - 1024) * DIM);
  float s = 0.f;
#pragma unroll
  for (int q = 0; q < 4; ++q) {
    float4 v = *reinterpret_cast<const float4*>(src + q * 256 + lane * 4);
    s += v.x * v.x + v.y * v.y + v.z * v.z + v.w * v.w;
  }
  float tot = dpp_reduce_bcast(s);
  if (lane == 0) {
    float val = 2.0f / tot;
    if (gw < 1024) tinu[gw] = val; else tinv[gw - 1024] = val;
  }
}

__global__ __launch_bounds__(256) void sig_k(const float* __restrict__ p, float* __restrict__ sg) {
  int i = blockIdx.x * 256 + threadIdx.x;
  if (i < DIM) {
    sg[i] = 0.1f + 0.9f / (1.0f + __expf(-p[i]));  // 0.9*sigmoid(p)+0.1
  }
}

// ---------------------------------------------------------------------------
// Pairwise dots for groups of 8 reflectors in APPLICATION ORDER.
// idx(a,b) = OFF[a] + b-a-1, 28 per group. 128 groups per side.
__global__ __launch_bounds__(256) void pairs_k(const float* __restrict__ U,
                                               const float* __restrict__ V,
                                               float* __restrict__ cU,
                                               float* __restrict__ cV) {
  int gw = (blockIdx.x * 256 + threadIdx.x) >> 6;
  int lane = threadIdx.x & 63;
  if (gw >= 256) return;
  int isV = gw >= 128;
  int g = isV ? gw - 128 : gw;
  const float* R = isV ? V : U;
  int r0 = isV ? (DIM - 1 - 8 * g) : 8 * g;
  int dir = isV ? -1 : 1;
  float u[8][16];
#pragma unroll
  for (int rr = 0; rr < 8; ++rr) {
    const float* src = R + (size_t)(r0 + dir * rr) * DIM;
#pragma unroll
    for (int q = 0; q < 4; ++q) {
      float4 v = *reinterpret_cast<const float4*>(src + q * 256 + lane * 4);
      u[rr][q * 4 + 0] = v.x; u[rr][q * 4 + 1] = v.y;
      u[rr][q * 4 + 2] = v.z; u[rr][q * 4 + 3] = v.w;
    }
  }
  const int PA[28] = {0,0,0,0,0,0,0, 1,1,1,1,1,1, 2,2,2,2,2, 3,3,3,3, 4,4,4, 5,5, 6};
  const int PB[28] = {1,2,3,4,5,6,7, 2,3,4,5,6,7, 3,4,5,6,7, 4,5,6,7, 5,6,7, 6,7, 7};
  float* dst = (isV ? cV : cU) + (size_t)g * 28;
#pragma unroll
  for (int b = 0; b < 7; ++b) {
    float s[4];
#pragma unroll
    for (int t = 0; t < 4; ++t) {
      int k = b * 4 + t;
      float a = 0.f;
#pragma unroll
      for (int i = 0; i < 16; ++i) a = fmaf(u[PA[k]][i], u[PB[k]][i], a);
      s[t] = a;
    }
    dpp_reduce4_bcast(s);
    if (lane == 0) {
      dst[b * 4 + 0] = s[0]; dst[b * 4 + 1] = s[1];
      dst[b * 4 + 2] = s[2]; dst[b * 4 + 3] = s[3];
    }
  }
}

// ---------------------------------------------------------------------------
// chain_k helpers. Register layout: reg q*4+j <-> elem q*256 + lane*4 + j.
template <int CMIN, int DIR>
__device__ __forceinline__ void load4(float (&u)[4][16], const float* __restrict__ R,
                                      int o, int lane) {
  int r0 = (DIR > 0) ? o : (DIM - 1 - o);
#pragma unroll
  for (int rr = 0; rr < 4; ++rr) {
    const float* src = R + (size_t)(r0 + DIR * rr) * DIM;
#pragma unroll
    for (int q = 0; q < 4; ++q) {
      if (q >= CMIN) {
        float4 v = *reinterpret_cast<const float4*>(src + q * 256 + lane * 4);
        u[rr][q * 4 + 0] = v.x; u[rr][q * 4 + 1] = v.y;
        u[rr][q * 4 + 2] = v.z; u[rr][q * 4 + 3] = v.w;
      }
    }
  }
}

template <int CMIN>
__device__ __forceinline__ float dotrow(const float (&t)[16], const float (&u)[16]) {
  float a0 = 0.f, a1 = 0.f, a2 = 0.f, a3 = 0.f;
#pragma unroll
  for (int q = 0; q < 4; ++q) {
    if (q >= CMIN) {
      a0 = fmaf(t[q * 4 + 0], u[q * 4 + 0], a0);
      a1 = fmaf(t[q * 4 + 1], u[q * 4 + 1], a1);
      a2 = fmaf(t[q * 4 + 2], u[q * 4 + 2], a2);
      a3 = fmaf(t[q * 4 + 3], u[q * 4 + 3], a3);
    }
  }
  return (a0 + a1) + (a2 + a3);
}

template <int CMIN>
__device__ __forceinline__ void axpy4(float (&t)[16], const float (&u)[4][16],
                                      const float* al) {
#pragma unroll
  for (int q = 0; q < 4; ++q) {
    if (q >= CMIN) {
#pragma unroll
      for (int j = 0; j < 4; ++j) {
        int i = q * 4 + j;
        t[i] = fmaf(-al[3], u[3][i],
               fmaf(-al[2], u[2][i],
               fmaf(-al[1], u[1][i],
               fmaf(-al[0], u[0][i], t[i]))));
      }
    }
  }
}

// One phase = 256 reflections = 32 groups of 8 (compact-WY per group).
// c[] and taus[] read directly (wave-uniform -> scalar loads, no VGPR copies).
// Substitution fully hand-unrolled with literal c-indices (no scratch).
template <int CMIN, int DIR>
__device__ __forceinline__ void run_phase8(float (&t)[16], const float* __restrict__ R,
                                           int o0,
                                           const float* __restrict__ taus,
                                           const float* __restrict__ cg,
                                           int lane) {
  float A[4][16], B[4][16];
  load4<CMIN, DIR>(A, R, o0, lane);
  load4<CMIN, DIR>(B, R, o0 + 4, lane);
  for (int g = 0; g < 32; ++g) {
    int o = o0 + g * 8;
    int r0 = (DIR > 0) ? o : (DIM - 1 - o);
    const float* c = cg + (size_t)(o >> 3) * 28;
    float d[8];
#pragma unroll
    for (int rr = 0; rr < 4; ++rr) d[rr] = dotrow<CMIN>(t, A[rr]);
#pragma unroll
    for (int rr = 0; rr < 4; ++rr) d[4 + rr] = dotrow<CMIN>(t, B[rr]);
    dpp_reduce4_bcast(&d[0]);
    dpp_reduce4_bcast(&d[4]);
    // forward substitution through the group T-matrix (c idx = OFF[a]+b-a-1,
    // OFF = {0,7,13,18,22,25,27})
    float al[8];
    al[0] = taus[r0] * d[0];
    al[1] = taus[r0 + DIR] *
            fmaf(-al[0], c[0], d[1]);
    al[2] = taus[r0 + 2 * DIR] *
            fmaf(-al[1], c[7], fmaf(-al[0], c[1], d[2]));
    al[3] = taus[r0 + 3 * DIR] *
            fmaf(-al[2], c[13], fmaf(-al[1], c[8], fmaf(-al[0], c[2], d[3])));
    al[4] = taus[r0 + 4 * DIR] *
            fmaf(-al[3], c[18], fmaf(-al[2], c[14],
            fmaf(-al[1], c[9], fmaf(-al[0], c[3], d[4]))));
    al[5] = taus[r0 + 5 * DIR] *
            fmaf(-al[4], c[22], fmaf(-al[3], c[19], fmaf(-al[2], c[15],
            fmaf(-al[1], c[10], fmaf(-al[0], c[4], d[5])))));
    al[6] = taus[r0 + 6 * DIR] *
            fmaf(-al[5], c[25], fmaf(-al[4], c[23], fmaf(-al[3], c[20],
            fmaf(-al[2], c[16], fmaf(-al[1], c[11],
            fmaf(-al[0], c[5], d[6]))))));
    al[7] = taus[r0 + 7 * DIR] *
            fmaf(-al[6], c[27], fmaf(-al[5], c[26], fmaf(-al[4], c[24],
            fmaf(-al[3], c[21], fmaf(-al[2], c[17], fmaf(-al[1], c[12],
            fmaf(-al[0], c[6], d[7])))))));
    axpy4<CMIN>(t, A, &al[0]);
    if (g != 31) load4<CMIN, DIR>(A, R, o + 8, lane);
    axpy4<CMIN>(t, B, &al[4]);
    if (g != 31) load4<CMIN, DIR>(B, R, o + 12, lane);
  }
}

// Build QU' = (H0..H1023)*D rows (blocks 0..1023) and QV = (Hv1023..Hv0)
// rows (blocks 1024..2047). 2048 waves -> 2 waves/SIMD.
// NOTE: __launch_bounds__(64) with NO waves-per-EU arg. Evidence across
// rounds: a second arg of 1 capped hardware occupancy at 1 wave/SIMD
// (R2/R3/R6 all ~11%); plain (64) reached 19% (R4). VGPR unconstrained
// here (~140-190 expected) still allows the full 8 grid-waves/CU.
__global__ __launch_bounds__(64) void chain_k(const float* __restrict__ U,
                                              const float* __restrict__ V,
                                              const float* __restrict__ tinu,
                                              const float* __restrict__ tinv,
                                              const float* __restrict__ sg,
                                              const float* __restrict__ cU,
                                              const float* __restrict__ cV,
                                              float* __restrict__ QUp,
                                              float* __restrict__ QV) {
  const int gw = blockIdx.x;
  const int row = gw & (DIM - 1);
  const int lane = threadIdx.x;
  float t[16];
#pragma unroll
  for (int q = 0; q < 4; ++q)
#pragma unroll
    for (int j = 0; j < 4; ++j)
      t[q * 4 + j] = ((q * 256 + lane * 4 + j) == row) ? 1.0f : 0.0f;

  float* dst;
  if (gw < DIM) {
    run_phase8<0, 1>(t, U, 0, tinu, cU, lane);
    run_phase8<1, 1>(t, U, 256, tinu, cU, lane);
    run_phase8<2, 1>(t, U, 512, tinu, cU, lane);
    run_phase8<3, 1>(t, U, 768, tinu, cU, lane);
#pragma unroll
    for (int q = 0; q < 4; ++q) {
      float4 v = *reinterpret_cast<const float4*>(sg + q * 256 + lane * 4);
      t[q * 4 + 0] *= v.x; t[q * 4 + 1] *= v.y; t[q * 4 + 2] *= v.z; t[q * 4 + 3] *= v.w;
    }
    dst = QUp + (size_t)row * DIM;
  } else {
    run_phase8<3, -1>(t, V, 0, tinv, cV, lane);
    run_phase8<2, -1>(t, V, 256, tinv, cV, lane);
    run_phase8<1, -1>(t, V, 512, tinv, cV, lane);
    run_phase8<0, -1>(t, V, 768, tinv, cV, lane);
    dst = QV + (size_t)row * DIM;
  }
#pragma unroll
  for (int q = 0; q < 4; ++q) {
    float4 v;
    v.x = t[q * 4 + 0]; v.y = t[q * 4 + 1]; v.z = t[q * 4 + 2]; v.w = t[q * 4 + 3];
    *reinterpret_cast<float4*>(dst + q * 256 + lane * 4) = v;
  }
}

// ---------------------------------------------------------------------------
// Transpose + bf16 hi/lo split: Out*[n][k] = split(In[k][n]).
__global__ __launch_bounds__(256) void mtsplit_k(const float* __restrict__ M,
                                                 short* __restrict__ Mthi,
                                                 short* __restrict__ Mtlo) {
  __shared__ float tile[64][68];
  const int tr = blockIdx.y;  // k-tile
  const int tc = blockIdx.x;  // n-tile
  const int f = threadIdx.x;
#pragma unroll
  for (int ii = 0; ii < 4; ++ii) {
    int flat = f + ii * 256;
    int r = flat >> 4, c4 = (flat & 15) << 2;
    float4 v = *reinterpret_cast<const float4*>(M + (size_t)(tr * 64 + r) * DIM + tc * 64 + c4);
    tile[r][c4 + 0] = v.x; tile[r][c4 + 1] = v.y; tile[r][c4 + 2] = v.z; tile[r][c4 + 3] = v.w;
  }
  __syncthreads();
#pragma unroll
  for (int ii = 0; ii < 2; ++ii) {
    int flat = f + ii * 256;
    int nn = flat >> 3, k8 = (flat & 7) << 3;
    short8v vh, vl;
#pragma unroll
    for (int j = 0; j < 8; ++j) {
      float fv = tile[k8 + j][nn];
      short hh = f2bf(fv);
      vh[j] = hh;
      vl[j] = f2bf(fv - bf2f(hh));
    }
    size_t off = (size_t)(tc * 64 + nn) * DIM + tr * 64 + k8;
    *reinterpret_cast<short8v*>(Mthi + off) = vh;
    *reinterpret_cast<short8v*>(Mtlo + off) = vl;
  }
}

// ---------------------------------------------------------------------------
// M^T = (QU' @ QV)^T via split-bf16 MFMA; writes Mthi/Mtlo [n][k] directly.
// A = QU' (f32, split on the fly); B = QVt hi/lo (pre-split [n][k]).
__global__ __launch_bounds__(256) void mgemm_mfma_k(const float* __restrict__ A,
                                                    const short* __restrict__ Bthi,
                                                    const short* __restrict__ Btlo,
                                                    short* __restrict__ Mthi,
                                                    short* __restrict__ Mtlo) {
  __shared__ short Ah[128][40], Al[128][40], Bh[128][40], Bl[128][40];
  const int tid = threadIdx.x;
  const int bn = blockIdx.x;  // 0..7
  const int bm = blockIdx.y;  // 0..7
  const int wid = tid >> 6;
  const int wr = wid >> 1, wc = wid & 1;
  const int lane = tid & 63;
  const int l15 = lane & 15;
  const int k8 = (lane >> 4) << 3;

  f32x4 acc[4][4] = {};

  for (int kb = 0; kb < DIM; kb += 32) {
    __syncthreads();
#pragma unroll
    for (int ii = 0; ii < 4; ++ii) {
      int flat = tid + ii * 256;
      int r = flat >> 3, kq = (flat & 7) << 2;
      float4 v = *reinterpret_cast<const float4*>(
          A + (size_t)(bm * 128 + r) * DIM + kb + kq);
      short4v h, l;
      float fv[4] = {v.x, v.y, v.z, v.w};
#pragma unroll
      for (int j = 0; j < 4; ++j) {
        short hh = f2bf(fv[j]);
        h[j] = hh;
        l[j] = f2bf(fv[j] - bf2f(hh));
      }
      *reinterpret_cast<short4v*>(&Ah[r][kq]) = h;
      *reinterpret_cast<short4v*>(&Al[r][kq]) = l;
    }
#pragma unroll
    for (int ii = 0; ii < 2; ++ii) {
      int flat = tid + ii * 256;
      int n = flat >> 2, kk8 = (flat & 3) << 3;
      size_t off = (size_t)(bn * 128 + n) * DIM + kb + kk8;
      *reinterpret_cast<short8v*>(&Bh[n][kk8]) =
          *reinterpret_cast<const short8v*>(Bthi + off);
      *reinterpret_cast<short8v*>(&Bl[n][kk8]) =
          *reinterpret_cast<const short8v*>(Btlo + off);
    }
    __syncthreads();

    short8v ah[4], al_[4], bh[4], bl_[4];
#pragma unroll
    for (int m = 0; m < 4; ++m) {
      int r = wr * 64 + m * 16 + l15;
      ah[m] = *reinterpret_cast<const short8v*>(&Ah[r][k8]);
      al_[m] = *reinterpret_cast<const short8v*>(&Al[r][k8]);
    }
#pragma unroll
    for (int n = 0; n < 4; ++n) {
      int r = wc * 64 + n * 16 + l15;
      bh[n] = *reinterpret_cast<const short8v*>(&Bh[r][k8]);
      bl_[n] = *reinterpret_cast<const short8v*>(&Bl[r][k8]);
    }
#pragma unroll
    for (int m = 0; m < 4; ++m)
#pragma unroll
      for (int n = 0; n < 4; ++n) {
        acc[m][n] = __builtin_amdgcn_mfma_f32_16x16x32_bf16(ah[m], bh[n], acc[m][n], 0, 0, 0);
        acc[m][n] = __builtin_amdgcn_mfma_f32_16x16x32_bf16(ah[m], bl_[n], acc[m][n], 0, 0, 0);
        acc[m][n] = __builtin_amdgcn_mfma_f32_16x16x32_bf16(al_[m], bh[n], acc[m][n], 0, 0, 0);
      }
  }

  // epilogue: frag row (k of M) = (lane>>4)*4 + j contiguous -> packed 8B
  // stores of M^T[n][k] hi/lo.
#pragma unroll
  for (int n = 0; n < 4; ++n) {
    int gcol = bn * 128 + wc * 64 + n * 16 + l15;  // n index of M
#pragma unroll
    for (int m = 0; m < 4; ++m) {
      int gk0 = bm * 128 + wr * 64 + m * 16 + ((lane >> 4) << 2);  // k index
      short4v h, l;
#pragma unroll
      for (int j = 0; j < 4; ++j) {
        float fv = acc[m][n][j];
        short hh = f2bf(fv);
        h[j] = hh;
        l[j] = f2bf(fv - bf2f(hh));
      }
      *reinterpret_cast<short4v*>(Mthi + (size_t)gcol * DIM + gk0) = h;
      *reinterpret_cast<short4v*>(Mtlo + (size_t)gcol * DIM + gk0) = l;
    }
  }
}

// ---------------------------------------------------------------------------
// out[4096,1024] = x @ M + bias via split-bf16 MFMA:
// C = xh@Mh + xh@Ml + xl@Mh. 128x128 tile, BK=32, 4 waves, 4x4 16x16 frags.
__global__ __launch_bounds__(256) void gemm_mfma_k(const float* __restrict__ x,
                                                   const short* __restrict__ Bthi,
                                                   const short* __restrict__ Btlo,
                                                   const float* __restrict__ bias,
                                                   float* __restrict__ out) {
  __shared__ short Ah[128][40], Al[128][40], Bh[128][40], Bl[128][40];
  const int tid = threadIdx.x;
  const int bn = blockIdx.x;  // 0..7
  const int bm = blockIdx.y;  // 0..31
  const int wid = tid >> 6;
  const int wr = wid >> 1, wc = wid & 1;
  const int lane = tid & 63;
  const int l15 = lane & 15;
  const int k8 = (lane >> 4) << 3;

  f32x4 acc[4][4] = {};

  for (int kb = 0; kb < DIM; kb += 32) {
    __syncthreads();
    // stage A (x -> hi/lo bf16), 128 rows x 32 k
#pragma unroll
    for (int ii = 0; ii < 4; ++ii) {
      int flat = tid + ii * 256;           // 0..1023
      int r = flat >> 3, kq = (flat & 7) << 2;
      float4 v = *reinterpret_cast<const float4*>(
          x + (size_t)(bm * 128 + r) * DIM + kb + kq);
      short4v h, l;
      float fv[4] = {v.x, v.y, v.z, v.w};
#pragma unroll
      for (int j = 0; j < 4; ++j) {
        short hh = f2bf(fv[j]);
        h[j] = hh;
        l[j] = f2bf(fv[j] - bf2f(hh));
      }
      *reinterpret_cast<short4v*>(&Ah[r][kq]) = h;
      *reinterpret_cast<short4v*>(&Al[r][kq]) = l;
    }
    // stage B (Mt already bf16), 128 n x 32 k
#pragma unroll
    for (int ii = 0; ii < 2; ++ii) {
      int flat = tid + ii * 256;           // 0..511
      int n = flat >> 2, kk8 = (flat & 3) << 3;
      size_t off = (size_t)(bn * 128 + n) * DIM + kb + kk8;
      *reinterpret_cast<short8v*>(&Bh[n][kk8]) =
          *reinterpret_cast<const short8v*>(Bthi + off);
      *reinterpret_cast<short8v*>(&Bl[n][kk8]) =
          *reinterpret_cast<const short8v*>(Btlo + off);
    }
    __syncthreads();

    short8v ah[4], al_[4], bh[4], bl_[4];
#pragma unroll
    for (int m = 0; m < 4; ++m) {
      int r = wr * 64 + m * 16 + l15;
      ah[m] = *reinterpret_cast<const short8v*>(&Ah[r][k8]);
      al_[m] = *reinterpret_cast<const short8v*>(&Al[r][k8]);
    }
#pragma unroll
    for (int n = 0; n < 4; ++n) {
      int r = wc * 64 + n * 16 + l15;
      bh[n] = *reinterpret_cast<const short8v*>(&Bh[r][k8]);
      bl_[n] = *reinterpret_cast<const short8v*>(&Bl[r][k8]);
    }
#pragma unroll
    for (int m = 0; m < 4; ++m)
#pragma unroll
      for (int n = 0; n < 4; ++n) {
        acc[m][n] = __builtin_amdgcn_mfma_f32_16x16x32_bf16(ah[m], bh[n], acc[m][n], 0, 0, 0);
        acc[m][n] = __builtin_amdgcn_mfma_f32_16x16x32_bf16(ah[m], bl_[n], acc[m][n], 0, 0, 0);
        acc[m][n] = __builtin_amdgcn_mfma_f32_16x16x32_bf16(al_[m], bh[n], acc[m][n], 0, 0, 0);
      }
  }

  // epilogue: C row = (lane>>4)*4 + j, col = lane&15 (m89-verified layout)
#pragma unroll
  for (int n = 0; n < 4; ++n) {
    int gcol = bn * 128 + wc * 64 + n * 16 + l15;
    float bv = bias[gcol];
#pragma unroll
    for (int m = 0; m < 4; ++m) {
      int grow0 = bm * 128 + wr * 64 + m * 16 + ((lane >> 4) << 2);
#pragma unroll
      for (int j = 0; j < 4; ++j) {
        out[(size_t)(grow0 + j) * DIM + gcol] = acc[m][n][j] + bv;
      }
    }
  }
}

// ---------------------------------------------------------------------------
extern "C" void kernel_launch(void* const* d_in, const int* in_sizes, int n_in,
                              void* d_out, int out_size, void* d_ws, size_t ws_size,
                              hipStream_t stream) {
  const float* x    = (const float*)d_in[0];
  const float* U    = (const float*)d_in[1];
  const float* V    = (const float*)d_in[2];
  const float* p    = (const float*)d_in[3];
  const float* bias = (const float*)d_in[4];
  float* out = (float*)d_out;

  float* ws = (float*)d_ws;
  // Regions (float units):
  //   [0,1M)  QUp (f32)
  //   [1M,2M) QV (f32) -> dead after vsplit -> reused for Mthi/Mtlo
  //   [2M,3M) QVthi/QVtlo (2M shorts)
  //   [3M,..) smalls
  float* QUp   = ws;
  float* QV    = ws + (size_t)DIM * DIM;
  short* Mthi  = (short*)QV;
  short* Mtlo  = (short*)QV + (size_t)DIM * DIM;
  short* QVthi = (short*)(ws + 2 * (size_t)DIM * DIM);
  short* QVtlo = QVthi + (size_t)DIM * DIM;
  float* tinu  = ws + 3 * (size_t)DIM * DIM;
  float* tinv  = tinu + DIM;
  float* sg    = tinv + DIM;
  float* cU    = sg + DIM;          // 128*28
  float* cV    = cU + 128 * 28;     // 128*28

  prep_k<<<512, 256, 0, stream>>>(U, V, tinu, tinv);
  sig_k<<<DIM / 256, 256, 0, stream>>>(p, sg);
  pairs_k<<<64, 256, 0, stream>>>(U, V, cU, cV);
  chain_k<<<2 * DIM, 64, 0, stream>>>(U, V, tinu, tinv, sg, cU, cV, QUp, QV);
  mtsplit_k<<<dim3(16, 16), 256, 0, stream>>>(QV, QVthi, QVtlo);
  mgemm_mfma_k<<<dim3(8, 8), 256, 0, stream>>>(QUp, QVthi, QVtlo, Mthi, Mtlo);
  gemm_mfma_k<<<dim3(8, 32), 256, 0, stream>>>(x, Mthi, Mtlo, bias, out);
}

// Round 8
// 311.660 us; speedup vs baseline: 1.4433x; 1.4433x over previous
//
#include <hip/hip_runtime.h>

#define DIM 1024
#define BATCH 4096

typedef __attribute__((ext_vector_type(8))) short short8v;
typedef __attribute__((ext_vector_type(4))) short short4v;
typedef __attribute__((ext_vector_type(4))) float f32x4;

// ---------------------------------------------------------------------------
// DPP wave-wide reductions (VALU pipe; result wave-uniform via readlane 63).
__device__ __forceinline__ float dpp_reduce_bcast(float x) {
  int v = __builtin_bit_cast(int, x);
#define DPP_STEP(ctrl)                                                        \
  {                                                                           \
    int s = __builtin_amdgcn_update_dpp(0, v, ctrl, 0xf, 0xf, true);          \
    v = __builtin_bit_cast(                                                   \
        int, __builtin_bit_cast(float, v) + __builtin_bit_cast(float, s));    \
  }
  DPP_STEP(0x111) DPP_STEP(0x112) DPP_STEP(0x114) DPP_STEP(0x118)
  DPP_STEP(0x142) DPP_STEP(0x143)
#undef DPP_STEP
  return __builtin_bit_cast(float, __builtin_amdgcn_readlane(v, 63));
}

// 4 interleaved reduce chains.
__device__ __forceinline__ void dpp_reduce4_bcast(float* d) {
  int v0 = __builtin_bit_cast(int, d[0]);
  int v1 = __builtin_bit_cast(int, d[1]);
  int v2 = __builtin_bit_cast(int, d[2]);
  int v3 = __builtin_bit_cast(int, d[3]);
#define STEP4(ctrl)                                                           \
  {                                                                           \
    int s0 = __builtin_amdgcn_update_dpp(0, v0, ctrl, 0xf, 0xf, true);        \
    int s1 = __builtin_amdgcn_update_dpp(0, v1, ctrl, 0xf, 0xf, true);        \
    int s2 = __builtin_amdgcn_update_dpp(0, v2, ctrl, 0xf, 0xf, true);        \
    int s3 = __builtin_amdgcn_update_dpp(0, v3, ctrl, 0xf, 0xf, true);        \
    v0 = __builtin_bit_cast(int, __builtin_bit_cast(float, v0) +              \
                                     __builtin_bit_cast(float, s0));          \
    v1 = __builtin_bit_cast(int, __builtin_bit_cast(float, v1) +              \
                                     __builtin_bit_cast(float, s1));          \
    v2 = __builtin_bit_cast(int, __builtin_bit_cast(float, v2) +              \
                                     __builtin_bit_cast(float, s2));          \
    v3 = __builtin_bit_cast(int, __builtin_bit_cast(float, v3) +              \
                                     __builtin_bit_cast(float, s3));          \
  }
  STEP4(0x111) STEP4(0x112) STEP4(0x114) STEP4(0x118) STEP4(0x142) STEP4(0x143)
#undef STEP4
  d[0] = __builtin_bit_cast(float, __builtin_amdgcn_readlane(v0, 63));
  d[1] = __builtin_bit_cast(float, __builtin_amdgcn_readlane(v1, 63));
  d[2] = __builtin_bit_cast(float, __builtin_amdgcn_readlane(v2, 63));
  d[3] = __builtin_bit_cast(float, __builtin_amdgcn_readlane(v3, 63));
}

// 8 interleaved reduce chains (for R=2 row blocking: 4 dots x 2 rows).
__device__ __forceinline__ void dpp_reduce8_bcast(float* d) {
  int v[8];
#pragma unroll
  for (int i = 0; i < 8; ++i) v[i] = __builtin_bit_cast(int, d[i]);
#define STEP8(ctrl)                                                           \
  {                                                                           \
    int s[8];                                                                 \
    _Pragma("unroll") for (int i = 0; i < 8; ++i)                             \
        s[i] = __builtin_amdgcn_update_dpp(0, v[i], ctrl, 0xf, 0xf, true);    \
    _Pragma("unroll") for (int i = 0; i < 8; ++i)                             \
        v[i] = __builtin_bit_cast(int, __builtin_bit_cast(float, v[i]) +      \
                                           __builtin_bit_cast(float, s[i]));  \
  }
  STEP8(0x111) STEP8(0x112) STEP8(0x114) STEP8(0x118) STEP8(0x142) STEP8(0x143)
#undef STEP8
#pragma unroll
  for (int i = 0; i < 8; ++i)
    d[i] = __builtin_bit_cast(float, __builtin_amdgcn_readlane(v[i], 63));
}

// bf16 split helpers (RNE).
__device__ __forceinline__ short f2bf(float f) {
  unsigned u = __builtin_bit_cast(unsigned, f);
  u += 0x7FFFu + ((u >> 16) & 1u);
  return (short)(u >> 16);
}
__device__ __forceinline__ float bf2f(short h) {
  unsigned u = ((unsigned)(unsigned short)h) << 16;
  return __builtin_bit_cast(float, u);
}

// ---------------------------------------------------------------------------
// 2/||row||^2 for all rows of U and V. One wave per row.
__global__ __launch_bounds__(256) void prep_k(const float* __restrict__ U,
                                              const float* __restrict__ V,
                                              float* __restrict__ tinu,
                                              float* __restrict__ tinv) {
  int gw = (blockIdx.x * 256 + threadIdx.x) >> 6;
  int lane = threadIdx.x & 63;
  if (gw >= 2048) return;
  const float* src = (gw < 1024) ? (U + (size_t)gw * DIM) : (V + (size_t)(gw - 1024) * DIM);
  float s = 0.f;
#pragma unroll
  for (int q = 0; q < 4; ++q) {
    float4 v = *reinterpret_cast<const float4*>(src + q * 256 + lane * 4);
    s += v.x * v.x + v.y * v.y + v.z * v.z + v.w * v.w;
  }
  float tot = dpp_reduce_bcast(s);
  if (lane == 0) {
    float val = 2.0f / tot;
    if (gw < 1024) tinu[gw] = val; else tinv[gw - 1024] = val;
  }
}

__global__ __launch_bounds__(256) void sig_k(const float* __restrict__ p, float* __restrict__ sg) {
  int i = blockIdx.x * 256 + threadIdx.x;
  if (i < DIM) {
    sg[i] = 0.1f + 0.9f / (1.0f + __expf(-p[i]));  // 0.9*sigmoid(p)+0.1
  }
}

// ---------------------------------------------------------------------------
// Pairwise dots c_ab = u_a . u_b (a<b) per group of 4 consecutive reflectors
// IN APPLICATION ORDER (U ascending, V descending). Layout: (01,02,03,12,13,23).
__global__ __launch_bounds__(256) void pairs_k(const float* __restrict__ U,
                                               const float* __restrict__ V,
                                               float* __restrict__ cU,
                                               float* __restrict__ cV) {
  int gw = (blockIdx.x * 256 + threadIdx.x) >> 6;
  int lane = threadIdx.x & 63;
  if (gw >= 512) return;
  int isV = gw >= 256;
  int g = isV ? gw - 256 : gw;
  const float* R = isV ? V : U;
  int r0 = isV ? (DIM - 1 - 4 * g) : 4 * g;
  int dir = isV ? -1 : 1;
  float u[4][16];
#pragma unroll
  for (int rr = 0; rr < 4; ++rr) {
    const float* src = R + (size_t)(r0 + dir * rr) * DIM;
#pragma unroll
    for (int q = 0; q < 4; ++q) {
      float4 v = *reinterpret_cast<const float4*>(src + q * 256 + lane * 4);
      u[rr][q * 4 + 0] = v.x; u[rr][q * 4 + 1] = v.y;
      u[rr][q * 4 + 2] = v.z; u[rr][q * 4 + 3] = v.w;
    }
  }
  const int pa[6] = {0, 0, 0, 1, 1, 2};
  const int pb[6] = {1, 2, 3, 2, 3, 3};
  float* dst = (isV ? cV : cU) + (size_t)g * 6;
#pragma unroll
  for (int k = 0; k < 6; ++k) {
    float s = 0.f;
#pragma unroll
    for (int i = 0; i < 16; ++i) s = fmaf(u[pa[k]][i], u[pb[k]][i], s);
    s = dpp_reduce_bcast(s);
    if (lane == 0) dst[k] = s;
  }
}

// ---------------------------------------------------------------------------
// chain_k helpers. Register layout: reg q*4+j <-> elem q*256 + lane*4 + j.
template <int CMIN, int DIR>
__device__ __forceinline__ void load4(float (&u)[4][16], const float* __restrict__ R,
                                      int o, int lane) {
  int r0 = (DIR > 0) ? o : (DIM - 1 - o);
#pragma unroll
  for (int rr = 0; rr < 4; ++rr) {
    const float* src = R + (size_t)(r0 + DIR * rr) * DIM;
#pragma unroll
    for (int q = 0; q < 4; ++q) {
      if (q >= CMIN) {
        float4 v = *reinterpret_cast<const float4*>(src + q * 256 + lane * 4);
        u[rr][q * 4 + 0] = v.x; u[rr][q * 4 + 1] = v.y;
        u[rr][q * 4 + 2] = v.z; u[rr][q * 4 + 3] = v.w;
      }
    }
  }
}

template <int CMIN>
__device__ __forceinline__ float dotrow(const float (&t)[16], const float (&u)[16]) {
  float a0 = 0.f, a1 = 0.f, a2 = 0.f, a3 = 0.f;
#pragma unroll
  for (int q = 0; q < 4; ++q) {
    if (q >= CMIN) {
      a0 = fmaf(t[q * 4 + 0], u[q * 4 + 0], a0);
      a1 = fmaf(t[q * 4 + 1], u[q * 4 + 1], a1);
      a2 = fmaf(t[q * 4 + 2], u[q * 4 + 2], a2);
      a3 = fmaf(t[q * 4 + 3], u[q * 4 + 3], a3);
    }
  }
  return (a0 + a1) + (a2 + a3);
}

template <int CMIN>
__device__ __forceinline__ void axpy4(float (&t)[16], const float (&u)[4][16],
                                      const float* al) {
#pragma unroll
  for (int q = 0; q < 4; ++q) {
    if (q >= CMIN) {
#pragma unroll
      for (int j = 0; j < 4; ++j) {
        int i = q * 4 + j;
        t[i] = fmaf(-al[3], u[3][i],
               fmaf(-al[2], u[2][i],
               fmaf(-al[1], u[1][i],
               fmaf(-al[0], u[0][i], t[i]))));
      }
    }
  }
}

// Apply one group of 4 reflectors (compact-WY) to TWO accumulator rows.
// 8 independent dot/reduce chains pipeline through the VALU; the substitution
// c-values are shared (wave-uniform SGPR loads).
template <int CMIN, int DIR>
__device__ __forceinline__ void apply_group2(float (&t0)[16], float (&t1)[16],
                                             const float (&u)[4][16], int o,
                                             const float* __restrict__ taus,
                                             const float* __restrict__ cg) {
  int r0 = (DIR > 0) ? o : (DIM - 1 - o);
  const float* c = cg + (size_t)(o >> 2) * 6;
  float d[8];
#pragma unroll
  for (int rr = 0; rr < 4; ++rr) d[rr] = dotrow<CMIN>(t0, u[rr]);
#pragma unroll
  for (int rr = 0; rr < 4; ++rr) d[4 + rr] = dotrow<CMIN>(t1, u[rr]);
  dpp_reduce8_bcast(d);
  float tu0 = taus[r0], tu1 = taus[r0 + DIR];
  float tu2 = taus[r0 + 2 * DIR], tu3 = taus[r0 + 3 * DIR];
  float al[4], be[4];
  al[0] = tu0 * d[0];
  al[1] = tu1 * fmaf(-al[0], c[0], d[1]);
  al[2] = tu2 * fmaf(-al[1], c[3], fmaf(-al[0], c[1], d[2]));
  al[3] = tu3 * fmaf(-al[2], c[5], fmaf(-al[1], c[4], fmaf(-al[0], c[2], d[3])));
  be[0] = tu0 * d[4];
  be[1] = tu1 * fmaf(-be[0], c[0], d[5]);
  be[2] = tu2 * fmaf(-be[1], c[3], fmaf(-be[0], c[1], d[6]));
  be[3] = tu3 * fmaf(-be[2], c[5], fmaf(-be[1], c[4], fmaf(-be[0], c[2], d[7])));
  axpy4<CMIN>(t0, u, al);
  axpy4<CMIN>(t1, u, be);
}

// One phase = 256 reflections = 64 groups of 4, R=2 rows, double-buffered
// reflector prefetch (cover for B-load = the full apply of A, ~2x longer
// with R=2 than the proven R4 structure).
template <int CMIN, int DIR>
__device__ __forceinline__ void run_phase2(float (&t0)[16], float (&t1)[16],
                                           const float* __restrict__ R,
                                           int o0, int o1,
                                           const float* __restrict__ taus,
                                           const float* __restrict__ cg,
                                           int lane) {
  float A[4][16], B[4][16];
  load4<CMIN, DIR>(A, R, o0, lane);
  for (int o = o0; o < o1; o += 8) {
    load4<CMIN, DIR>(B, R, o + 4, lane);
    apply_group2<CMIN, DIR>(t0, t1, A, o, taus, cg);
    if (o + 8 < o1) load4<CMIN, DIR>(A, R, o + 8, lane);
    apply_group2<CMIN, DIR>(t0, t1, B, o + 4, taus, cg);
  }
}

// Build QU' = (H0..H1023)*D rows (blocks 0..511: rows 2b,2b+1) and
// QV = (Hv1023..Hv0) rows (blocks 512..1023). Each wave carries TWO
// accumulator rows -> reflector traffic through registers halves (the
// measured wall: 2048 waves x 2.6MB = 5.4GB through the load pipe).
__global__ __launch_bounds__(64) void chain_k(const float* __restrict__ U,
                                              const float* __restrict__ V,
                                              const float* __restrict__ tinu,
                                              const float* __restrict__ tinv,
                                              const float* __restrict__ sg,
                                              const float* __restrict__ cU,
                                              const float* __restrict__ cV,
                                              float* __restrict__ QUp,
                                              float* __restrict__ QV) {
  const int gw = blockIdx.x;
  const int row0 = (gw & 511) * 2;
  const int row1 = row0 + 1;
  const int lane = threadIdx.x;
  float t0[16], t1[16];
#pragma unroll
  for (int q = 0; q < 4; ++q)
#pragma unroll
    for (int j = 0; j < 4; ++j) {
      int e = q * 256 + lane * 4 + j;
      t0[q * 4 + j] = (e == row0) ? 1.0f : 0.0f;
      t1[q * 4 + j] = (e == row1) ? 1.0f : 0.0f;
    }

  float* dst;
  if (gw < 512) {
    run_phase2<0, 1>(t0, t1, U, 0, 256, tinu, cU, lane);
    run_phase2<1, 1>(t0, t1, U, 256, 512, tinu, cU, lane);
    run_phase2<2, 1>(t0, t1, U, 512, 768, tinu, cU, lane);
    run_phase2<3, 1>(t0, t1, U, 768, 1024, tinu, cU, lane);
    // fold D: scale columns by sg
#pragma unroll
    for (int q = 0; q < 4; ++q) {
      float4 v = *reinterpret_cast<const float4*>(sg + q * 256 + lane * 4);
      t0[q * 4 + 0] *= v.x; t0[q * 4 + 1] *= v.y; t0[q * 4 + 2] *= v.z; t0[q * 4 + 3] *= v.w;
      t1[q * 4 + 0] *= v.x; t1[q * 4 + 1] *= v.y; t1[q * 4 + 2] *= v.z; t1[q * 4 + 3] *= v.w;
    }
    dst = QUp;
  } else {
    run_phase2<3, -1>(t0, t1, V, 0, 256, tinv, cV, lane);
    run_phase2<2, -1>(t0, t1, V, 256, 512, tinv, cV, lane);
    run_phase2<1, -1>(t0, t1, V, 512, 768, tinv, cV, lane);
    run_phase2<0, -1>(t0, t1, V, 768, 1024, tinv, cV, lane);
    dst = QV;
  }
#pragma unroll
  for (int q = 0; q < 4; ++q) {
    float4 v0, v1;
    v0.x = t0[q * 4 + 0]; v0.y = t0[q * 4 + 1]; v0.z = t0[q * 4 + 2]; v0.w = t0[q * 4 + 3];
    v1.x = t1[q * 4 + 0]; v1.y = t1[q * 4 + 1]; v1.z = t1[q * 4 + 2]; v1.w = t1[q * 4 + 3];
    *reinterpret_cast<float4*>(dst + (size_t)row0 * DIM + q * 256 + lane * 4) = v0;
    *reinterpret_cast<float4*>(dst + (size_t)row1 * DIM + q * 256 + lane * 4) = v1;
  }
}

// ---------------------------------------------------------------------------
// Transpose + bf16 hi/lo split: Out*[n][k] = split(In[k][n]).
__global__ __launch_bounds__(256) void mtsplit_k(const float* __restrict__ M,
                                                 short* __restrict__ Mthi,
                                                 short* __restrict__ Mtlo) {
  __shared__ float tile[64][68];
  const int tr = blockIdx.y;  // k-tile
  const int tc = blockIdx.x;  // n-tile
  const int f = threadIdx.x;
#pragma unroll
  for (int ii = 0; ii < 4; ++ii) {
    int flat = f + ii * 256;
    int r = flat >> 4, c4 = (flat & 15) << 2;
    float4 v = *reinterpret_cast<const float4*>(M + (size_t)(tr * 64 + r) * DIM + tc * 64 + c4);
    tile[r][c4 + 0] = v.x; tile[r][c4 + 1] = v.y; tile[r][c4 + 2] = v.z; tile[r][c4 + 3] = v.w;
  }
  __syncthreads();
#pragma unroll
  for (int ii = 0; ii < 2; ++ii) {
    int flat = f + ii * 256;
    int nn = flat >> 3, k8 = (flat & 7) << 3;
    short8v vh, vl;
#pragma unroll
    for (int j = 0; j < 8; ++j) {
      float fv = tile[k8 + j][nn];
      short hh = f2bf(fv);
      vh[j] = hh;
      vl[j] = f2bf(fv - bf2f(hh));
    }
    size_t off = (size_t)(tc * 64 + nn) * DIM + tr * 64 + k8;
    *reinterpret_cast<short8v*>(Mthi + off) = vh;
    *reinterpret_cast<short8v*>(Mtlo + off) = vl;
  }
}

// ---------------------------------------------------------------------------
// M^T = (QU' @ QV)^T via split-bf16 MFMA; writes Mthi/Mtlo [n][k] directly.
__global__ __launch_bounds__(256) void mgemm_mfma_k(const float* __restrict__ A,
                                                    const short* __restrict__ Bthi,
                                                    const short* __restrict__ Btlo,
                                                    short* __restrict__ Mthi,
                                                    short* __restrict__ Mtlo) {
  __shared__ short Ah[128][40], Al[128][40], Bh[128][40], Bl[128][40];
  const int tid = threadIdx.x;
  const int bn = blockIdx.x;
  const int bm = blockIdx.y;
  const int wid = tid >> 6;
  const int wr = wid >> 1, wc = wid & 1;
  const int lane = tid & 63;
  const int l15 = lane & 15;
  const int k8 = (lane >> 4) << 3;

  f32x4 acc[4][4] = {};

  for (int kb = 0; kb < DIM; kb += 32) {
    __syncthreads();
#pragma unroll
    for (int ii = 0; ii < 4; ++ii) {
      int flat = tid + ii * 256;
      int r = flat >> 3, kq = (flat & 7) << 2;
      float4 v = *reinterpret_cast<const float4*>(
          A + (size_t)(bm * 128 + r) * DIM + kb + kq);
      short4v h, l;
      float fv[4] = {v.x, v.y, v.z, v.w};
#pragma unroll
      for (int j = 0; j < 4; ++j) {
        short hh = f2bf(fv[j]);
        h[j] = hh;
        l[j] = f2bf(fv[j] - bf2f(hh));
      }
      *reinterpret_cast<short4v*>(&Ah[r][kq]) = h;
      *reinterpret_cast<short4v*>(&Al[r][kq]) = l;
    }
#pragma unroll
    for (int ii = 0; ii < 2; ++ii) {
      int flat = tid + ii * 256;
      int n = flat >> 2, kk8 = (flat & 3) << 3;
      size_t off = (size_t)(bn * 128 + n) * DIM + kb + kk8;
      *reinterpret_cast<short8v*>(&Bh[n][kk8]) =
          *reinterpret_cast<const short8v*>(Bthi + off);
      *reinterpret_cast<short8v*>(&Bl[n][kk8]) =
          *reinterpret_cast<const short8v*>(Btlo + off);
    }
    __syncthreads();

    short8v ah[4], al_[4], bh[4], bl_[4];
#pragma unroll
    for (int m = 0; m < 4; ++m) {
      int r = wr * 64 + m * 16 + l15;
      ah[m] = *reinterpret_cast<const short8v*>(&Ah[r][k8]);
      al_[m] = *reinterpret_cast<const short8v*>(&Al[r][k8]);
    }
#pragma unroll
    for (int n = 0; n < 4; ++n) {
      int r = wc * 64 + n * 16 + l15;
      bh[n] = *reinterpret_cast<const short8v*>(&Bh[r][k8]);
      bl_[n] = *reinterpret_cast<const short8v*>(&Bl[r][k8]);
    }
#pragma unroll
    for (int m = 0; m < 4; ++m)
#pragma unroll
      for (int n = 0; n < 4; ++n) {
        acc[m][n] = __builtin_amdgcn_mfma_f32_16x16x32_bf16(ah[m], bh[n], acc[m][n], 0, 0, 0);
        acc[m][n] = __builtin_amdgcn_mfma_f32_16x16x32_bf16(ah[m], bl_[n], acc[m][n], 0, 0, 0);
        acc[m][n] = __builtin_amdgcn_mfma_f32_16x16x32_bf16(al_[m], bh[n], acc[m][n], 0, 0, 0);
      }
  }

#pragma unroll
  for (int n = 0; n < 4; ++n) {
    int gcol = bn * 128 + wc * 64 + n * 16 + l15;  // n index of M
#pragma unroll
    for (int m = 0; m < 4; ++m) {
      int gk0 = bm * 128 + wr * 64 + m * 16 + ((lane >> 4) << 2);  // k index
      short4v h, l;
#pragma unroll
      for (int j = 0; j < 4; ++j) {
        float fv = acc[m][n][j];
        short hh = f2bf(fv);
        h[j] = hh;
        l[j] = f2bf(fv - bf2f(hh));
      }
      *reinterpret_cast<short4v*>(Mthi + (size_t)gcol * DIM + gk0) = h;
      *reinterpret_cast<short4v*>(Mtlo + (size_t)gcol * DIM + gk0) = l;
    }
  }
}

// ---------------------------------------------------------------------------
// out[4096,1024] = x @ M + bias via split-bf16 MFMA.
__global__ __launch_bounds__(256) void gemm_mfma_k(const float* __restrict__ x,
                                                   const short* __restrict__ Bthi,
                                                   const short* __restrict__ Btlo,
                                                   const float* __restrict__ bias,
                                                   float* __restrict__ out) {
  __shared__ short Ah[128][40], Al[128][40], Bh[128][40], Bl[128][40];
  const int tid = threadIdx.x;
  const int bn = blockIdx.x;
  const int bm = blockIdx.y;
  const int wid = tid >> 6;
  const int wr = wid >> 1, wc = wid & 1;
  const int lane = tid & 63;
  const int l15 = lane & 15;
  const int k8 = (lane >> 4) << 3;

  f32x4 acc[4][4] = {};

  for (int kb = 0; kb < DIM; kb += 32) {
    __syncthreads();
#pragma unroll
    for (int ii = 0; ii < 4; ++ii) {
      int flat = tid + ii * 256;
      int r = flat >> 3, kq = (flat & 7) << 2;
      float4 v = *reinterpret_cast<const float4*>(
          x + (size_t)(bm * 128 + r) * DIM + kb + kq);
      short4v h, l;
      float fv[4] = {v.x, v.y, v.z, v.w};
#pragma unroll
      for (int j = 0; j < 4; ++j) {
        short hh = f2bf(fv[j]);
        h[j] = hh;
        l[j] = f2bf(fv[j] - bf2f(hh));
      }
      *reinterpret_cast<short4v*>(&Ah[r][kq]) = h;
      *reinterpret_cast<short4v*>(&Al[r][kq]) = l;
    }
#pragma unroll
    for (int ii = 0; ii < 2; ++ii) {
      int flat = tid + ii * 256;
      int n = flat >> 2, kk8 = (flat & 3) << 3;
      size_t off = (size_t)(bn * 128 + n) * DIM + kb + kk8;
      *reinterpret_cast<short8v*>(&Bh[n][kk8]) =
          *reinterpret_cast<const short8v*>(Bthi + off);
      *reinterpret_cast<short8v*>(&Bl[n][kk8]) =
          *reinterpret_cast<const short8v*>(Btlo + off);
    }
    __syncthreads();

    short8v ah[4], al_[4], bh[4], bl_[4];
#pragma unroll
    for (int m = 0; m < 4; ++m) {
      int r = wr * 64 + m * 16 + l15;
      ah[m] = *reinterpret_cast<const short8v*>(&Ah[r][k8]);
      al_[m] = *reinterpret_cast<const short8v*>(&Al[r][k8]);
    }
#pragma unroll
    for (int n = 0; n < 4; ++n) {
      int r = wc * 64 + n * 16 + l15;
      bh[n] = *reinterpret_cast<const short8v*>(&Bh[r][k8]);
      bl_[n] = *reinterpret_cast<const short8v*>(&Bl[r][k8]);
    }
#pragma unroll
    for (int m = 0; m < 4; ++m)
#pragma unroll
      for (int n = 0; n < 4; ++n) {
        acc[m][n] = __builtin_amdgcn_mfma_f32_16x16x32_bf16(ah[m], bh[n], acc[m][n], 0, 0, 0);
        acc[m][n] = __builtin_amdgcn_mfma_f32_16x16x32_bf16(ah[m], bl_[n], acc[m][n], 0, 0, 0);
        acc[m][n] = __builtin_amdgcn_mfma_f32_16x16x32_bf16(al_[m], bh[n], acc[m][n], 0, 0, 0);
      }
  }

#pragma unroll
  for (int n = 0; n < 4; ++n) {
    int gcol = bn * 128 + wc * 64 + n * 16 + l15;
    float bv = bias[gcol];
#pragma unroll
    for (int m = 0; m < 4; ++m) {
      int grow0 = bm * 128 + wr * 64 + m * 16 + ((lane >> 4) << 2);
#pragma unroll
      for (int j = 0; j < 4; ++j) {
        out[(size_t)(grow0 + j) * DIM + gcol] = acc[m][n][j] + bv;
      }
    }
  }
}

// ---------------------------------------------------------------------------
extern "C" void kernel_launch(void* const* d_in, const int* in_sizes, int n_in,
                              void* d_out, int out_size, void* d_ws, size_t ws_size,
                              hipStream_t stream) {
  const float* x    = (const float*)d_in[0];
  const float* U    = (const float*)d_in[1];
  const float* V    = (const float*)d_in[2];
  const float* p    = (const float*)d_in[3];
  const float* bias = (const float*)d_in[4];
  float* out = (float*)d_out;

  float* ws = (float*)d_ws;
  float* QUp   = ws;
  float* QV    = ws + (size_t)DIM * DIM;
  short* Mthi  = (short*)QV;                        // reuse QV after split
  short* Mtlo  = (short*)QV + (size_t)DIM * DIM;
  short* QVthi = (short*)(ws + 2 * (size_t)DIM * DIM);
  short* QVtlo = QVthi + (size_t)DIM * DIM;
  float* tinu  = ws + 3 * (size_t)DIM * DIM;
  float* tinv  = tinu + DIM;
  float* sg    = tinv + DIM;
  float* cU    = sg + DIM;          // 256*6
  float* cV    = cU + 256 * 6;      // 256*6

  prep_k<<<512, 256, 0, stream>>>(U, V, tinu, tinv);
  sig_k<<<DIM / 256, 256, 0, stream>>>(p, sg);
  pairs_k<<<128, 256, 0, stream>>>(U, V, cU, cV);
  chain_k<<<1024, 64, 0, stream>>>(U, V, tinu, tinv, sg, cU, cV, QUp, QV);
  mtsplit_k<<<dim3(16, 16), 256, 0, stream>>>(QV, QVthi, QVtlo);
  mgemm_mfma_k<<<dim3(8, 8), 256, 0, stream>>>(QUp, QVthi, QVtlo, Mthi, Mtlo);
  gemm_mfma_k<<<dim3(8, 32), 256, 0, stream>>>(x, Mthi, Mtlo, bias, out);
}